// Round 16
// baseline (215.334 us; speedup 1.0000x reference)
//
#include <hip/hip_runtime.h>

typedef unsigned short u16;
typedef __bf16 bf16x8 __attribute__((ext_vector_type(8)));
typedef float f32x4 __attribute__((ext_vector_type(4)));
typedef unsigned short u16x8 __attribute__((ext_vector_type(8)));

#define QKV_N 5120
#define SEQ 2048
#define ATTN_K 4096
#define K1 2880     // = 45*64 exactly
#define SCALE 0.125f
#define NEGINF -1e30f

__device__ __forceinline__ u16 f2bf(float f) {
  unsigned int u = __builtin_bit_cast(unsigned int, f);
  u = (u + 0x7FFFu + ((u >> 16) & 1u)) >> 16;
  return (u16)u;
}
__device__ __forceinline__ float bf2f(u16 u) {
  unsigned int x = ((unsigned int)u) << 16;
  return __builtin_bit_cast(float, x);
}

#define MFMA16(a, b, c) __builtin_amdgcn_mfma_f32_16x16x32_bf16((a), (b), (c), 0, 0, 0)

// async global->LDS, 16B per lane; LDS dest = wave-uniform base + lane*16
__device__ __forceinline__ void gl_lds16(const u16* g, u16* l) {
  __builtin_amdgcn_global_load_lds(
      (const __attribute__((address_space(1))) unsigned int*)(const void*)g,
      (__attribute__((address_space(3))) unsigned int*)(void*)l, 16, 0, 0);
}

// fragment read from [rows][32k] half-tile (64B rows); swizzle key (row>>1)&3
__device__ __forceinline__ bf16x8 fragrd(const u16* base, int row, int rb) {
  return *(const bf16x8*)((const char*)(base + row * 32) + rb);
}

// legacy frag read for GEMM2's [rows][64k] swizzled tile (128B rows)
__device__ __forceinline__ bf16x8 lds_frag(const u16* mat, int row, int kh, int lg) {
  int off = row * 128 + ((kh * 64 + lg * 16) ^ ((row & 7) << 4));
  return *(const bf16x8*)((const char*)mat + off);
}

// ========== merged prep: rope table | convert | transpose wqkv | transpose wo ======
__global__ __launch_bounds__(256) void k_prep(const int* __restrict__ pos,
                                              float2* __restrict__ tab,
                                              const float* __restrict__ hs,
                                              u16* __restrict__ hsb,
                                              const float* __restrict__ wqkv,
                                              u16* __restrict__ wqkvT,
                                              const float* __restrict__ wo,
                                              u16* __restrict__ woT) {
  __shared__ float tile[32][33];
  const int blk = blockIdx.x;
  if (blk < 256) {
    int t = blk * 256 + threadIdx.x;  // 65536 = 2048*32
    int s = t >> 5, i = t & 31;
    float freq = powf(150000.0f, -(float)i * (1.0f / 32.0f));
    float ang = (float)pos[s] * freq;
    float sv, cv;
    sincosf(ang, &sv, &cv);
    tab[t] = make_float2(cv, sv);
  } else if (blk < 6016) {
    int i = (blk - 256) * 256 + threadIdx.x;  // 2048*720 u16x4 units
    float4 v = *(const float4*)(hs + (size_t)i * 4);
    ushort4 o;
    o.x = f2bf(v.x); o.y = f2bf(v.y); o.z = f2bf(v.z); o.w = f2bf(v.w);
    ((ushort4*)hsb)[i] = o;
  } else {
    const float* in;
    u16* out;
    int Kin, Kout, Nd, Npad, bx, by;
    if (blk < 20416) {
      int q = blk - 6016;  // 160 x 90
      bx = q % 160; by = q / 160;
      in = wqkv; out = wqkvT; Kin = 2880; Kout = K1; Nd = 5120; Npad = 5120;
    } else {
      int q = blk - 20416;  // 92 x 128
      bx = q % 92; by = q / 92;
      in = wo; out = woT; Kin = 4096; Kout = 4096; Nd = 2880; Npad = 2944;
    }
    int n0 = bx * 32, k0 = by * 32;
    int c = threadIdx.x & 31, r0 = threadIdx.x >> 5;
#pragma unroll
    for (int j = 0; j < 4; j++) {
      int r = r0 + j * 8;
      float v = 0.f;
      if (n0 + c < Nd && k0 + r < Kin) v = in[(size_t)(k0 + r) * Nd + n0 + c];
      tile[r][c] = v;
    }
    __syncthreads();
#pragma unroll
    for (int j = 0; j < 4; j++) {
      int rr = r0 + j * 8;
      int n = n0 + rr;
      if (n < Npad) out[(size_t)n * Kout + k0 + c] = f2bf(tile[c][rr]);
    }
  }
}

// ======== GEMM1: 128x160, grid 512 (2/CU), BK=64, 45 tiles, 4-phase ========
// A DIRECT FROM GLOBAL (L2): per-wave register ping-pong, loaded 1 phase ahead.
// B via LDS (2 bufs x 20KB, swizzled). Exact-counted vmcnt per phase.
// Queue invariant entering each tile: exactly [X(2)] (A-pair for p0) in flight.
__global__ __launch_bounds__(256, 2) void k_gemm1(const u16* __restrict__ Ag,
                                                  const u16* __restrict__ Bg,
                                                  const float* __restrict__ bias,
                                                  u16* __restrict__ C) {
  __shared__ u16 lds_[2][10240];  // [buf][2kh x 160 rows x 32 k] B only
  u16* L = &lds_[0][0];
  const int tid = threadIdx.x;
  const int lane = tid & 63, wave = tid >> 6;
  const int wm = wave >> 1, wn = wave & 1;
  const int lr = lane & 15, lg = lane >> 4;
  const int bid = blockIdx.x;
  const int xcd = bid & 7, j = bid >> 3;       // 512 = 8 XCD x 64
  const int m0 = (j >> 2) * 128;               // 16 m-tiles
  const int n0 = (xcd * 4 + (j & 3)) * 160;    // 32 n-tiles, 4 per XCD

  f32x4 acc[4][5] = {};
  bf16x8 Bf[5], X0, X1, Y0, Y1;

  const int rb = (lg * 16) ^ (((lr >> 1) & 3) << 4);  // B frag-read swizzled byte off

  // A direct-load base: wave's rows (wm*64 + mf*16 + lr), k-chunk lg*8.
  // A wave frag read = 16 rows x 64B contiguous (lg packs adjacent 16B) -> coalesced.
  const u16* aA = Ag + (size_t)(m0 + wm * 64 + lr) * K1 + lg * 8;

  // B staging: 5 rounds per tile over linear [kh0 5120 | kh1 5120] region
  size_t boff[5];
#pragma unroll
  for (int r_ = 0; r_ < 5; r_++) {
    int e = r_ * 2048 + tid * 8;
    int bkh = (e >= 5120) ? 1 : 0;
    int re = e - bkh * 5120;
    int brow = re >> 5;
    int bch = (re >> 3) & 3;
    int bps = bch ^ ((brow >> 1) & 3);
    boff[r_] = (size_t)(n0 + brow) * K1 + bkh * 32 + bps * 8;
  }

#define STB(b, kt, r_)                                                          \
  gl_lds16(Bg + boff[r_] + (kt), L + (b) * 10240 + (r_) * 2048 + wave * 512)
#define RDB(b, kh)                                                              \
  { _Pragma("unroll") for (int nf = 0; nf < 5; nf++)                            \
      Bf[nf] = fragrd(L + (b) * 10240 + (kh) * 5120,                            \
                      wn * 80 + nf * 16 + lr, rb); }
#define LDA(d0, d1, mf0_, kk)                                                   \
  { d0 = *(const bf16x8*)(aA + (size_t)(mf0_) * 16 * K1 + (kk));                \
    d1 = *(const bf16x8*)(aA + (size_t)((mf0_) + 1) * 16 * K1 + (kk)); }
#define MM(Aa, Ab, ma, mb)                                                      \
  { __builtin_amdgcn_s_setprio(1);                                              \
    _Pragma("unroll") for (int nf = 0; nf < 5; nf++) {                          \
      acc[ma][nf] = MFMA16(Aa, Bf[nf], acc[ma][nf]);                            \
      acc[mb][nf] = MFMA16(Ab, Bf[nf], acc[mb][nf]); }                          \
    __builtin_amdgcn_s_setprio(0); }
#define BAR __builtin_amdgcn_s_barrier();
#define VM6 asm volatile("s_waitcnt vmcnt(6)" ::: "memory");
#define VM5 asm volatile("s_waitcnt vmcnt(5)" ::: "memory");
#define VM4 asm volatile("s_waitcnt vmcnt(4)" ::: "memory");
#define VM2 asm volatile("s_waitcnt vmcnt(2)" ::: "memory");
#define VM0 asm volatile("s_waitcnt vmcnt(0)" ::: "memory");

  // prologue: B tile0 -> buf0 (S0..S4); A p0 pair (X). Drain S, keep X in flight.
  STB(0, 0, 0); STB(0, 0, 1); STB(0, 0, 2); STB(0, 0, 3); STB(0, 0, 4);
  LDA(X0, X1, 0, 0)
  VM2 BAR

  for (int t = 0; t < 45; t++) {
    const int b = t & 1, nb = b ^ 1;
    const int kt = t * 64, kt1 = kt + 64;
    const bool st = (t < 44);
    // p0 (kh0, mf01 via X): prefetch Y=kh0 mf23; stage S0,S1
    RDB(b, 0)
    LDA(Y0, Y1, 2, kt)
    if (st) { STB(nb, kt1, 0); STB(nb, kt1, 1); VM4 } else { VM2 }
    BAR MM(X0, X1, 0, 1) BAR
    // p1 (kh0, mf23 via Y): prefetch X=kh1 mf01; stage S2,S3
    LDA(X0, X1, 0, kt + 32)
    if (st) { STB(nb, kt1, 2); STB(nb, kt1, 3); VM6 } else { VM2 }
    BAR MM(Y0, Y1, 2, 3) BAR
    // p2 (kh1, mf01 via X): prefetch Y=kh1 mf23; stage S4
    RDB(b, 1)
    LDA(Y0, Y1, 2, kt + 32)
    if (st) { STB(nb, kt1, 4); VM5 } else { VM2 }
    BAR MM(X0, X1, 0, 1) BAR
    // p3 (kh1, mf23 via Y): prefetch next-tile X; certify S0..S4 + Y
    if (st) { LDA(X0, X1, 0, kt1) VM2 } else { VM0 }
    BAR MM(Y0, Y1, 2, 3) BAR
  }
#undef STB
#undef RDB
#undef LDA
#undef MM
#undef VM6
#undef VM5
#undef VM4
#undef VM2
#undef VM0

  // ---- epilogue: bias, bf16 store ----
#pragma unroll
  for (int mf = 0; mf < 4; mf++)
#pragma unroll
    for (int nf = 0; nf < 5; nf++) {
      int col = n0 + wn * 80 + nf * 16 + lr;
      float bv = bias[col];
#pragma unroll
      for (int rg = 0; rg < 4; rg++) {
        int row = m0 + wm * 64 + mf * 16 + lg * 4 + rg;
        C[(size_t)row * QKV_N + col] = f2bf(acc[mf][nf][rg] + bv);
      }
    }
}

// ======== GEMM2 (round-13 proven): 128x96, grid 480, 2-tile ring, counted vmcnt ====
// A = attn bf16 [2048][4096], B = woT bf16 [2944][4096], C f32 [2048][2880].
__global__ __launch_bounds__(256, 2) void k_gemm2(const u16* __restrict__ Ag,
                                                  const u16* __restrict__ Bg,
                                                  const float* __restrict__ bias,
                                                  float* __restrict__ C) {
  __shared__ u16 ldsbuf[2][14336];  // [buf][A 8192 | B 6144]
  const int tid = threadIdx.x;
  const int lane = tid & 63, wave = tid >> 6;
  const int wm = wave >> 1, wn = wave & 1;
  const int lr = lane & 15, lg = lane >> 4;
  int bid = blockIdx.x;
  int l = (bid & 7) * 60 + (bid >> 3);  // 480 = 8 XCD x 60, n-major
  const int m0 = (l & 15) * 128, n0 = (l >> 4) * 96;

  f32x4 acc[4][3] = {};

  const int srow = wave * 8 + (lane >> 3);         // within 32-row round
  const int sc = ((lane & 7) ^ (lane >> 3)) << 3;  // pre-swizzled chunk
  const u16* gA = Ag + (size_t)(m0 + srow) * ATTN_K + sc;
  const u16* gB = Bg + (size_t)(n0 + srow) * ATTN_K + sc;

#define G2_STAGE(kt, b)                                                          \
  {                                                                              \
    u16* Ab = &ldsbuf[b][0];                                                     \
    u16* Bb = &ldsbuf[b][8192];                                                  \
    _Pragma("unroll") for (int r = 0; r < 4; r++)                                \
      gl_lds16(gA + (size_t)(r * 32) * ATTN_K + (kt), Ab + (r * 32 + wave * 8) * 64); \
    _Pragma("unroll") for (int r = 0; r < 3; r++)                                \
      gl_lds16(gB + (size_t)(r * 32) * ATTN_K + (kt), Bb + (r * 32 + wave * 8) * 64); \
  }

  G2_STAGE(0, 0)
  G2_STAGE(64, 1)
  asm volatile("s_waitcnt vmcnt(7)" ::: "memory");
  __builtin_amdgcn_s_barrier();

  for (int t = 0; t < 64; t++) {
    const int b = t & 1;
    const u16* La = &ldsbuf[b][0];
    const u16* Lb = &ldsbuf[b][8192];
    bf16x8 Bf[3][2];
#pragma unroll
    for (int nf = 0; nf < 3; nf++)
#pragma unroll
      for (int kh = 0; kh < 2; kh++)
        Bf[nf][kh] = lds_frag(Lb, wn * 48 + nf * 16 + lr, kh, lg);
    bf16x8 Af[2][2];
#pragma unroll
    for (int mi = 0; mi < 2; mi++)
#pragma unroll
      for (int kh = 0; kh < 2; kh++)
        Af[mi][kh] = lds_frag(La, wm * 64 + mi * 16 + lr, kh, lg);
#pragma unroll
    for (int q = 0; q < 2; q++) {
      bf16x8 An[2][2];
      if (q < 1) {
#pragma unroll
        for (int mi = 0; mi < 2; mi++)
#pragma unroll
          for (int kh = 0; kh < 2; kh++)
            An[mi][kh] = lds_frag(La, wm * 64 + ((q + 1) * 2 + mi) * 16 + lr, kh, lg);
      }
      __builtin_amdgcn_s_setprio(1);
#pragma unroll
      for (int mi = 0; mi < 2; mi++)
#pragma unroll
        for (int nf = 0; nf < 3; nf++)
#pragma unroll
          for (int kh = 0; kh < 2; kh++)
            acc[q * 2 + mi][nf] = MFMA16(Af[mi][kh], Bf[nf][kh], acc[q * 2 + mi][nf]);
      __builtin_amdgcn_s_setprio(0);
      if (q < 1) {
#pragma unroll
        for (int mi = 0; mi < 2; mi++)
#pragma unroll
          for (int kh = 0; kh < 2; kh++)
            Af[mi][kh] = An[mi][kh];
      }
    }
    __builtin_amdgcn_s_barrier();
    if (t <= 61) {
      G2_STAGE((t + 2) * 64, b)
      asm volatile("s_waitcnt vmcnt(7)" ::: "memory");
    } else {
      asm volatile("s_waitcnt vmcnt(0)" ::: "memory");
    }
    __builtin_amdgcn_s_barrier();
  }
#undef G2_STAGE

#pragma unroll
  for (int mi = 0; mi < 4; mi++)
#pragma unroll
    for (int ni = 0; ni < 3; ni++) {
      int row = m0 + wm * 64 + mi * 16 + lg * 4;
      int col = n0 + wn * 48 + ni * 16 + lr;
      float bv = bias[col];
#pragma unroll
      for (int rg = 0; rg < 4; rg++)
        C[(size_t)(row + rg) * 2880 + col] = acc[mi][ni][rg] + bv;
    }
}

// ---- attention QB=64 @ 512 thr (round-14 proven): stage 192 keys once; each of 8
// waves processes its head's TWO 32-query subtiles sequentially. RoPE fused.
__global__ __launch_bounds__(512, 2) void k_attn(const u16* __restrict__ qkv,
                                                 const float* __restrict__ sinks,
                                                 const float2* __restrict__ tab,
                                                 u16* __restrict__ out) {
  __shared__ u16 Klds[192 * 64];      // XOR-swizzled rows (24.0 KB)
  __shared__ u16 Vt[64 * 200];        // V transposed [d][key], padded (25.0 KB)
  __shared__ u16 Pslab[8 * 32 * 40];  // per-wave P bounce (20.0 KB)
  const int hk = blockIdx.y;
  const int s0 = blockIdx.x * 64;
  const int kb = s0 - 127;
  const int tid = threadIdx.x;
  const int lane = tid & 63, w = tid >> 6;
  const int lr = lane & 15, lg = lane >> 4;
  const int head = hk * 8 + w;

  // ---- stage K with fused RoPE: 192 keys x 4 chunk-pairs = 768 units ----
  for (int u = tid; u < 192 * 4; u += 512) {
    int key = u >> 2, c = u & 3;
    int kidx = kb + key;
    u16x8 v1 = {0, 0, 0, 0, 0, 0, 0, 0}, v2 = v1;
    if (kidx >= 0 && kidx < SEQ) {
      const u16* base = qkv + (size_t)kidx * QKV_N + 4096 + hk * 64;
      u16x8 x1 = *(const u16x8*)(base + c * 8);
      u16x8 x2 = *(const u16x8*)(base + 32 + c * 8);
      const float2* cs = tab + (size_t)kidx * 32 + c * 8;
#pragma unroll
      for (int jj = 0; jj < 8; jj++) {
        float f1 = bf2f(x1[jj]), f2 = bf2f(x2[jj]);
        float2 t = cs[jj];
        v1[jj] = f2bf(f1 * t.x - f2 * t.y);
        v2[jj] = f2bf(f2 * t.x + f1 * t.y);
      }
    }
    int o1 = (key * 128 + c * 16) ^ ((key & 7) << 4);
    int o2 = (key * 128 + (c + 4) * 16) ^ ((key & 7) << 4);
    *(u16x8*)((char*)Klds + o1) = v1;
    *(u16x8*)((char*)Klds + o2) = v2;
  }
  // ---- stage V (no rope): 192*16 units ----
  for (int e4 = tid; e4 < 192 * 16; e4 += 512) {
    int key = e4 >> 4, d0 = (e4 & 15) * 4;
    int kidx = kb + key;
    ushort4 v = {0, 0, 0, 0};
    if (kidx >= 0 && kidx < SEQ)
      v = *(const ushort4*)(qkv + (size_t)kidx * QKV_N + 4608 + hk * 64 + d0);
    Vt[(d0 + 0) * 200 + key] = v.x;
    Vt[(d0 + 1) * 200 + key] = v.y;
    Vt[(d0 + 2) * 200 + key] = v.z;
    Vt[(d0 + 3) * 200 + key] = v.w;
  }
  __syncthreads();

  const float sink = sinks[head];
  u16* slab = &Pslab[w * 32 * 40];
  f32x4 zz = {0.f, 0.f, 0.f, 0.f};

  for (int qs = 0; qs < 2; qs++) {
    const int qbase = s0 + qs * 32;   // query rows
    const int koff = qs * 32;         // staged-key window offset

    // ---- Q frags with in-register RoPE ----
    bf16x8 qf[2][2];
#pragma unroll
    for (int rt = 0; rt < 2; rt++) {
      int s = qbase + rt * 16 + lr;
      const u16* base = qkv + (size_t)s * QKV_N + head * 64 + lg * 8;
      u16x8 r0 = *(const u16x8*)(base);
      u16x8 r1 = *(const u16x8*)(base + 32);
      const float2* cs = tab + (size_t)s * 32 + lg * 8;
      u16x8 y0, y1;
#pragma unroll
      for (int jj = 0; jj < 8; jj++) {
        float f1 = bf2f(r0[jj]), f2 = bf2f(r1[jj]);
        float2 t = cs[jj];
        y0[jj] = f2bf(f1 * t.x - f2 * t.y);
        y1[jj] = f2bf(f2 * t.x + f1 * t.y);
      }
      qf[rt][0] = __builtin_bit_cast(bf16x8, y0);
      qf[rt][1] = __builtin_bit_cast(bf16x8, y1);
    }

    // ---- QK^T over this subtile's 160-key window ----
    f32x4 sc[2][10];
#pragma unroll
    for (int rt = 0; rt < 2; rt++)
#pragma unroll
      for (int nt = 0; nt < 10; nt++) sc[rt][nt] = zz;
#pragma unroll
    for (int nt = 0; nt < 10; nt++) {
      int key = koff + nt * 16 + lr;
#pragma unroll
      for (int ks = 0; ks < 2; ks++) {
        int off = (key * 128 + ks * 64 + lg * 16) ^ ((key & 7) << 4);
        bf16x8 kf = *(const bf16x8*)((const char*)Klds + off);
        sc[0][nt] = MFMA16(qf[0][ks], kf, sc[0][nt]);
        sc[1][nt] = MFMA16(qf[1][ks], kf, sc[1][nt]);
      }
    }

    // ---- mask + scale (subtile-local coords) ----
#pragma unroll
    for (int rt = 0; rt < 2; rt++)
#pragma unroll
      for (int nt = 0; nt < 10; nt++)
#pragma unroll
        for (int rg = 0; rg < 4; rg++) {
          int qq = rt * 16 + lg * 4 + rg;
          int jl = nt * 16 + lr;
          bool valid = (jl >= qq) && (jl <= qq + 127) && ((kb + koff + jl) >= 0);
          sc[rt][nt][rg] = valid ? sc[rt][nt][rg] * SCALE : NEGINF;
        }

    // ---- softmax ----
    float den[2][4];
#pragma unroll
    for (int rt = 0; rt < 2; rt++)
#pragma unroll
      for (int rg = 0; rg < 4; rg++) {
        float m = NEGINF;
#pragma unroll
        for (int nt = 0; nt < 10; nt++) m = fmaxf(m, sc[rt][nt][rg]);
#pragma unroll
        for (int x = 1; x < 16; x <<= 1) m = fmaxf(m, __shfl_xor(m, x, 64));
        m = fmaxf(m, sink);
        float sum = 0.f;
#pragma unroll
        for (int nt = 0; nt < 10; nt++) {
          float p = __expf(sc[rt][nt][rg] - m);
          sc[rt][nt][rg] = p;
          sum += p;
        }
#pragma unroll
        for (int x = 1; x < 16; x <<= 1) sum += __shfl_xor(sum, x, 64);
        den[rt][rg] = sum + __expf(sink - m);
      }

    // ---- PV over the window ----
    f32x4 oacc[2][4];
#pragma unroll
    for (int rt = 0; rt < 2; rt++)
#pragma unroll
      for (int dn = 0; dn < 4; dn++) oacc[rt][dn] = zz;
#pragma unroll
    for (int kt = 0; kt < 5; kt++) {
#pragma unroll
      for (int rt = 0; rt < 2; rt++)
#pragma unroll
        for (int j2 = 0; j2 < 2; j2++)
#pragma unroll
          for (int rg = 0; rg < 4; rg++)
            slab[(rt * 16 + lg * 4 + rg) * 40 + j2 * 16 + lr] =
                f2bf(sc[rt][kt * 2 + j2][rg]);
      asm volatile("s_waitcnt lgkmcnt(0)" ::: "memory");
      __builtin_amdgcn_sched_barrier(0);
      bf16x8 pf0 = *(const bf16x8*)&slab[lr * 40 + lg * 8];
      bf16x8 pf1 = *(const bf16x8*)&slab[(16 + lr) * 40 + lg * 8];
#pragma unroll
      for (int dn = 0; dn < 4; dn++) {
        bf16x8 vf = *(const bf16x8*)&Vt[(dn * 16 + lr) * 200 + koff + kt * 32 + lg * 8];
        oacc[0][dn] = MFMA16(pf0, vf, oacc[0][dn]);
        oacc[1][dn] = MFMA16(pf1, vf, oacc[1][dn]);
      }
    }

    // ---- write normalized output (bf16 for GEMM2) ----
#pragma unroll
    for (int rt = 0; rt < 2; rt++)
#pragma unroll
      for (int dn = 0; dn < 4; dn++)
#pragma unroll
        for (int rg = 0; rg < 4; rg++) {
          int s = qbase + rt * 16 + lg * 4 + rg;
          float val = oacc[rt][dn][rg] / den[rt][rg];
          out[(size_t)s * ATTN_K + head * 64 + dn * 16 + lr] = f2bf(val);
        }
  }
}

extern "C" void kernel_launch(void* const* d_in, const int* in_sizes, int n_in,
                              void* d_out, int out_size, void* d_ws, size_t ws_size,
                              hipStream_t stream) {
  const float* hs = (const float*)d_in[0];
  const int* pos = (const int*)d_in[1];
  const float* wqkv = (const float*)d_in[2];
  const float* bqkv = (const float*)d_in[3];
  const float* wo = (const float*)d_in[4];
  const float* bo = (const float*)d_in[5];
  const float* sinks = (const float*)d_in[6];
  float* out = (float*)d_out;

  char* ws = (char*)d_ws;
  u16* qkvb = (u16*)(ws + 0);               // 2048*5120*2 = 20,971,520 (bf16, un-roped)
  u16* hsb = (u16*)(ws + 41943040);         // 2048*2880*2 = 11,796,480 -> ends 53,739,520
  u16* wqkvT = (u16*)(ws + 53739520);       // 5120*2880*2 = 29,491,200 -> ends 83,230,720
  u16* attnb = (u16*)(ws + 41943040);       // 2048*4096*2 (aliases dead hsb/wqkvT)
  u16* woT = (u16*)(ws + 83230720);         // 2944*4096*2 = 24,117,248 -> ends 107,347,968
  float2* tab = (float2*)(ws + 107347968);  // 2048*32*8   = 524,288

  k_prep<<<32192, 256, 0, stream>>>(pos, tab, hs, hsb, wqkv, wqkvT, wo, woT);
  k_gemm1<<<512, 256, 0, stream>>>(hsb, wqkvT, bqkv, qkvb);
  k_attn<<<dim3(32, 8), 512, 0, stream>>>(qkvb, sinks, tab, attnb);
  k_gemm2<<<480, 256, 0, stream>>>(attnb, woT, bo, out);
}

// Round 17
// 179.732 us; speedup vs baseline: 1.1981x; 1.1981x over previous
//
#include <hip/hip_runtime.h>

typedef unsigned short u16;
typedef __bf16 bf16x8 __attribute__((ext_vector_type(8)));
typedef float f32x4 __attribute__((ext_vector_type(4)));
typedef unsigned short u16x8 __attribute__((ext_vector_type(8)));

#define QKV_N 5120
#define SEQ 2048
#define ATTN_K 4096
#define K1 2880     // = 45*64 exactly: NO padding needed
#define SCALE 0.125f
#define NEGINF -1e30f

__device__ __forceinline__ u16 f2bf(float f) {
  unsigned int u = __builtin_bit_cast(unsigned int, f);
  u = (u + 0x7FFFu + ((u >> 16) & 1u)) >> 16;
  return (u16)u;
}
__device__ __forceinline__ float bf2f(u16 u) {
  unsigned int x = ((unsigned int)u) << 16;
  return __builtin_bit_cast(float, x);
}

#define MFMA16(a, b, c) __builtin_amdgcn_mfma_f32_16x16x32_bf16((a), (b), (c), 0, 0, 0)

// async global->LDS, 16B per lane; LDS dest = wave-uniform base + lane*16
__device__ __forceinline__ void gl_lds16(const u16* g, u16* l) {
  __builtin_amdgcn_global_load_lds(
      (const __attribute__((address_space(1))) unsigned int*)(const void*)g,
      (__attribute__((address_space(3))) unsigned int*)(void*)l, 16, 0, 0);
}

// fragment read from [rows][32k] half-tile (64B rows); swizzle key (row>>1)&3
__device__ __forceinline__ bf16x8 fragrd(const u16* base, int row, int rb) {
  return *(const bf16x8*)((const char*)(base + row * 32) + rb);
}

// legacy frag read for GEMM2's [rows][64k] swizzled tile (128B rows)
__device__ __forceinline__ bf16x8 lds_frag(const u16* mat, int row, int kh, int lg) {
  int off = row * 128 + ((kh * 64 + lg * 16) ^ ((row & 7) << 4));
  return *(const bf16x8*)((const char*)mat + off);
}

// ========== merged prep: rope table | convert | transpose wqkv | transpose wo ======
// blocks [0,256): rope table; [256,6016): hs f32->bf16 (unpadded, 2048x720 u16x4);
// [6016,20416): wqkvT (160x90); [20416,32192): woT (92x128). Branch is block-uniform.
__global__ __launch_bounds__(256) void k_prep(const int* __restrict__ pos,
                                              float2* __restrict__ tab,
                                              const float* __restrict__ hs,
                                              u16* __restrict__ hsb,
                                              const float* __restrict__ wqkv,
                                              u16* __restrict__ wqkvT,
                                              const float* __restrict__ wo,
                                              u16* __restrict__ woT) {
  __shared__ float tile[32][33];
  const int blk = blockIdx.x;
  if (blk < 256) {
    int t = blk * 256 + threadIdx.x;  // 65536 = 2048*32
    int s = t >> 5, i = t & 31;
    float freq = powf(150000.0f, -(float)i * (1.0f / 32.0f));
    float ang = (float)pos[s] * freq;
    float sv, cv;
    sincosf(ang, &sv, &cv);
    tab[t] = make_float2(cv, sv);
  } else if (blk < 6016) {
    int i = (blk - 256) * 256 + threadIdx.x;  // 2048*720 u16x4 units
    float4 v = *(const float4*)(hs + (size_t)i * 4);
    ushort4 o;
    o.x = f2bf(v.x); o.y = f2bf(v.y); o.z = f2bf(v.z); o.w = f2bf(v.w);
    ((ushort4*)hsb)[i] = o;
  } else {
    const float* in;
    u16* out;
    int Kin, Kout, Nd, Npad, bx, by;
    if (blk < 20416) {
      int q = blk - 6016;  // 160 x 90
      bx = q % 160; by = q / 160;
      in = wqkv; out = wqkvT; Kin = 2880; Kout = K1; Nd = 5120; Npad = 5120;
    } else {
      int q = blk - 20416;  // 92 x 128
      bx = q % 92; by = q / 92;
      in = wo; out = woT; Kin = 4096; Kout = 4096; Nd = 2880; Npad = 2944;
    }
    int n0 = bx * 32, k0 = by * 32;
    int c = threadIdx.x & 31, r0 = threadIdx.x >> 5;
#pragma unroll
    for (int j = 0; j < 4; j++) {
      int r = r0 + j * 8;
      float v = 0.f;
      if (n0 + c < Nd && k0 + r < Kin) v = in[(size_t)(k0 + r) * Nd + n0 + c];
      tile[r][c] = v;
    }
    __syncthreads();
#pragma unroll
    for (int j = 0; j < 4; j++) {
      int rr = r0 + j * 8;
      int n = n0 + rr;
      if (n < Npad) out[(size_t)n * Kout + k0 + c] = f2bf(tile[c][rr]);
    }
  }
}

// ======== GEMM1: 128x160, grid 512 (2 blocks/CU), BK=64, 45 K-tiles, 4-phase ======
// A [2048][2880] bf16, B [5120][2880] bf16 (B^T), out qkv bf16 [2048][5120], bias only.
// XCD swizzle: n-major slices (4 B-panels per XCD stay L2-resident).
__global__ __launch_bounds__(256, 2) void k_gemm1(const u16* __restrict__ Ag,
                                                  const u16* __restrict__ Bg,
                                                  const float* __restrict__ bias,
                                                  u16* __restrict__ C) {
  __shared__ u16 lds_[2][18432];
  u16* L = &lds_[0][0];
  const int tid = threadIdx.x;
  const int lane = tid & 63, wave = tid >> 6;
  const int wm = wave >> 1, wn = wave & 1;
  const int lr = lane & 15, lg = lane >> 4;
  const int bid = blockIdx.x;
  const int xcd = bid & 7, j = bid >> 3;       // 512 = 8 XCD x 64
  const int m0 = (j >> 2) * 128;               // 16 m-tiles
  const int n0 = (xcd * 4 + (j & 3)) * 160;    // 32 n-tiles, 4 per XCD

  f32x4 acc[4][5] = {};
  bf16x8 Bf[5], Af0, Af1;

  const int rb = (lg * 16) ^ (((lr >> 1) & 3) << 4);      // frag-read swizzled byte off
  const int arow = tid >> 2;                              // A staging row within 64-round
  const int axs = ((tid & 3) ^ ((tid >> 3) & 3)) << 3;    // A pre-swizzled chunk (elems)

  // B staging: 5 rounds per tile over linear [kh0 5120 | kh1 5120] region
  size_t boff[5];
#pragma unroll
  for (int r_ = 0; r_ < 5; r_++) {
    int e = r_ * 2048 + tid * 8;
    int bkh = (e >= 5120) ? 1 : 0;
    int re = e - bkh * 5120;
    int brow = re >> 5;
    int bch = (re >> 3) & 3;
    int bps = bch ^ ((brow >> 1) & 3);
    boff[r_] = (size_t)(n0 + brow) * K1 + bkh * 32 + bps * 8;
  }

#define STA(b, kh, kt, r_)                                                      \
  gl_lds16(Ag + (size_t)(m0 + (r_) * 64 + arow) * K1 + (kt) + (kh) * 32 + axs,  \
           L + (b) * 18432 + (kh) * 4096 + (r_) * 2048 + wave * 512)
#define STB(b, kt, r_)                                                          \
  gl_lds16(Bg + boff[r_] + (kt), L + (b) * 18432 + 8192 + (r_) * 2048 + wave * 512)
#define RDB(b, kh)                                                              \
  { _Pragma("unroll") for (int nf = 0; nf < 5; nf++)                            \
      Bf[nf] = fragrd(L + (b) * 18432 + 8192 + (kh) * 5120,                     \
                      wn * 80 + nf * 16 + lr, rb); }
#define RDA(b, kh, mf0_)                                                        \
  { Af0 = fragrd(L + (b) * 18432 + (kh) * 4096, wm * 64 + (mf0_) * 16 + lr, rb); \
    Af1 = fragrd(L + (b) * 18432 + (kh) * 4096, wm * 64 + ((mf0_) + 1) * 16 + lr, rb); }
#define MM(ma, mb)                                                              \
  { __builtin_amdgcn_s_setprio(1);                                              \
    _Pragma("unroll") for (int nf = 0; nf < 5; nf++) {                          \
      acc[ma][nf] = MFMA16(Af0, Bf[nf], acc[ma][nf]);                           \
      acc[mb][nf] = MFMA16(Af1, Bf[nf], acc[mb][nf]); }                         \
    __builtin_amdgcn_s_setprio(0); }
#define BAR __builtin_amdgcn_s_barrier();
#define VM4 asm volatile("s_waitcnt vmcnt(4)" ::: "memory");
#define VM0 asm volatile("s_waitcnt vmcnt(0)" ::: "memory");

  // prologue: tile 0 -> buf0 (ops 1-9); certify ops 1-5 (A-kh0 + B r0..r2)
  STA(0, 0, 0, 0); STA(0, 0, 0, 1);
  STB(0, 0, 0); STB(0, 0, 1); STB(0, 0, 2); STB(0, 0, 3); STB(0, 0, 4);
  STA(0, 1, 0, 0); STA(0, 1, 0, 1);
  VM4 BAR

  for (int t = 0; t < 45; t++) {
    const int b = t & 1, nb = b ^ 1;
    const int kt1 = (t + 1) * 64;
    const bool st = (t < 44);
    RDB(b, 0) RDA(b, 0, 0)
    if (st) { STA(nb, 0, kt1, 0); STA(nb, 0, kt1, 1); STB(nb, kt1, 0); }
    BAR MM(0, 1) BAR
    RDA(b, 0, 2)
    if (st) { STB(nb, kt1, 1); STB(nb, kt1, 2); VM4 } else { VM0 }
    BAR MM(2, 3) BAR
    RDB(b, 1) RDA(b, 1, 0)
    if (st) { STB(nb, kt1, 3); STB(nb, kt1, 4); }
    BAR MM(0, 1) BAR
    RDA(b, 1, 2)
    if (st) { STA(nb, 1, kt1, 0); STA(nb, 1, kt1, 1); VM4 }
    BAR MM(2, 3) BAR
  }
#undef STA
#undef STB
#undef RDB
#undef RDA
#undef MM
#undef VM4
#undef VM0

  // ---- epilogue: bias, bf16 store ----
#pragma unroll
  for (int mf = 0; mf < 4; mf++)
#pragma unroll
    for (int nf = 0; nf < 5; nf++) {
      int col = n0 + wn * 80 + nf * 16 + lr;
      float bv = bias[col];
#pragma unroll
      for (int rg = 0; rg < 4; rg++) {
        int row = m0 + wm * 64 + mf * 16 + lg * 4 + rg;
        C[(size_t)row * QKV_N + col] = f2bf(acc[mf][nf][rg] + bv);
      }
    }
}

// ======== GEMM2 (round-13 proven): 128x96, grid 480, 2-tile ring, counted vmcnt ====
// A = attn bf16 [2048][4096], B = woT bf16 [2944][4096], C f32 [2048][2880].
__global__ __launch_bounds__(256, 2) void k_gemm2(const u16* __restrict__ Ag,
                                                  const u16* __restrict__ Bg,
                                                  const float* __restrict__ bias,
                                                  float* __restrict__ C) {
  __shared__ u16 ldsbuf[2][14336];  // [buf][A 8192 | B 6144]
  const int tid = threadIdx.x;
  const int lane = tid & 63, wave = tid >> 6;
  const int wm = wave >> 1, wn = wave & 1;
  const int lr = lane & 15, lg = lane >> 4;
  int bid = blockIdx.x;
  int l = (bid & 7) * 60 + (bid >> 3);  // 480 = 8 XCD x 60, n-major
  const int m0 = (l & 15) * 128, n0 = (l >> 4) * 96;

  f32x4 acc[4][3] = {};

  const int srow = wave * 8 + (lane >> 3);         // within 32-row round
  const int sc = ((lane & 7) ^ (lane >> 3)) << 3;  // pre-swizzled chunk
  const u16* gA = Ag + (size_t)(m0 + srow) * ATTN_K + sc;
  const u16* gB = Bg + (size_t)(n0 + srow) * ATTN_K + sc;

#define G2_STAGE(kt, b)                                                          \
  {                                                                              \
    u16* Ab = &ldsbuf[b][0];                                                     \
    u16* Bb = &ldsbuf[b][8192];                                                  \
    _Pragma("unroll") for (int r = 0; r < 4; r++)                                \
      gl_lds16(gA + (size_t)(r * 32) * ATTN_K + (kt), Ab + (r * 32 + wave * 8) * 64); \
    _Pragma("unroll") for (int r = 0; r < 3; r++)                                \
      gl_lds16(gB + (size_t)(r * 32) * ATTN_K + (kt), Bb + (r * 32 + wave * 8) * 64); \
  }

  G2_STAGE(0, 0)
  G2_STAGE(64, 1)
  asm volatile("s_waitcnt vmcnt(7)" ::: "memory");
  __builtin_amdgcn_s_barrier();

  for (int t = 0; t < 64; t++) {
    const int b = t & 1;
    const u16* La = &ldsbuf[b][0];
    const u16* Lb = &ldsbuf[b][8192];
    bf16x8 Bf[3][2];
#pragma unroll
    for (int nf = 0; nf < 3; nf++)
#pragma unroll
      for (int kh = 0; kh < 2; kh++)
        Bf[nf][kh] = lds_frag(Lb, wn * 48 + nf * 16 + lr, kh, lg);
    bf16x8 Af[2][2];
#pragma unroll
    for (int mi = 0; mi < 2; mi++)
#pragma unroll
      for (int kh = 0; kh < 2; kh++)
        Af[mi][kh] = lds_frag(La, wm * 64 + mi * 16 + lr, kh, lg);
#pragma unroll
    for (int q = 0; q < 2; q++) {
      bf16x8 An[2][2];
      if (q < 1) {
#pragma unroll
        for (int mi = 0; mi < 2; mi++)
#pragma unroll
          for (int kh = 0; kh < 2; kh++)
            An[mi][kh] = lds_frag(La, wm * 64 + ((q + 1) * 2 + mi) * 16 + lr, kh, lg);
      }
      __builtin_amdgcn_s_setprio(1);
#pragma unroll
      for (int mi = 0; mi < 2; mi++)
#pragma unroll
        for (int nf = 0; nf < 3; nf++)
#pragma unroll
          for (int kh = 0; kh < 2; kh++)
            acc[q * 2 + mi][nf] = MFMA16(Af[mi][kh], Bf[nf][kh], acc[q * 2 + mi][nf]);
      __builtin_amdgcn_s_setprio(0);
      if (q < 1) {
#pragma unroll
        for (int mi = 0; mi < 2; mi++)
#pragma unroll
          for (int kh = 0; kh < 2; kh++)
            Af[mi][kh] = An[mi][kh];
      }
    }
    __builtin_amdgcn_s_barrier();
    if (t <= 61) {
      G2_STAGE((t + 2) * 64, b)
      asm volatile("s_waitcnt vmcnt(7)" ::: "memory");
    } else {
      asm volatile("s_waitcnt vmcnt(0)" ::: "memory");
    }
    __builtin_amdgcn_s_barrier();
  }
#undef G2_STAGE

#pragma unroll
  for (int mi = 0; mi < 4; mi++)
#pragma unroll
    for (int ni = 0; ni < 3; ni++) {
      int row = m0 + wm * 64 + mi * 16 + lg * 4;
      int col = n0 + wn * 48 + ni * 16 + lr;
      float bv = bias[col];
#pragma unroll
      for (int rg = 0; rg < 4; rg++)
        C[(size_t)(row + rg) * 2880 + col] = acc[mi][ni][rg] + bv;
    }
}

// ---- attention QB=64 @ 512 thr (round-14 proven): stage 192 keys once; each of 8
// waves processes its head's TWO 32-query subtiles sequentially. RoPE fused.
__global__ __launch_bounds__(512, 2) void k_attn(const u16* __restrict__ qkv,
                                                 const float* __restrict__ sinks,
                                                 const float2* __restrict__ tab,
                                                 u16* __restrict__ out) {
  __shared__ u16 Klds[192 * 64];      // XOR-swizzled rows (24.0 KB)
  __shared__ u16 Vt[64 * 200];        // V transposed [d][key], padded (25.0 KB)
  __shared__ u16 Pslab[8 * 32 * 40];  // per-wave P bounce (20.0 KB)
  const int hk = blockIdx.y;
  const int s0 = blockIdx.x * 64;
  const int kb = s0 - 127;
  const int tid = threadIdx.x;
  const int lane = tid & 63, w = tid >> 6;
  const int lr = lane & 15, lg = lane >> 4;
  const int head = hk * 8 + w;

  // ---- stage K with fused RoPE: 192 keys x 4 chunk-pairs = 768 units ----
  for (int u = tid; u < 192 * 4; u += 512) {
    int key = u >> 2, c = u & 3;
    int kidx = kb + key;
    u16x8 v1 = {0, 0, 0, 0, 0, 0, 0, 0}, v2 = v1;
    if (kidx >= 0 && kidx < SEQ) {
      const u16* base = qkv + (size_t)kidx * QKV_N + 4096 + hk * 64;
      u16x8 x1 = *(const u16x8*)(base + c * 8);
      u16x8 x2 = *(const u16x8*)(base + 32 + c * 8);
      const float2* cs = tab + (size_t)kidx * 32 + c * 8;
#pragma unroll
      for (int jj = 0; jj < 8; jj++) {
        float f1 = bf2f(x1[jj]), f2 = bf2f(x2[jj]);
        float2 t = cs[jj];
        v1[jj] = f2bf(f1 * t.x - f2 * t.y);
        v2[jj] = f2bf(f2 * t.x + f1 * t.y);
      }
    }
    int o1 = (key * 128 + c * 16) ^ ((key & 7) << 4);
    int o2 = (key * 128 + (c + 4) * 16) ^ ((key & 7) << 4);
    *(u16x8*)((char*)Klds + o1) = v1;
    *(u16x8*)((char*)Klds + o2) = v2;
  }
  // ---- stage V (no rope): 192*16 units ----
  for (int e4 = tid; e4 < 192 * 16; e4 += 512) {
    int key = e4 >> 4, d0 = (e4 & 15) * 4;
    int kidx = kb + key;
    ushort4 v = {0, 0, 0, 0};
    if (kidx >= 0 && kidx < SEQ)
      v = *(const ushort4*)(qkv + (size_t)kidx * QKV_N + 4608 + hk * 64 + d0);
    Vt[(d0 + 0) * 200 + key] = v.x;
    Vt[(d0 + 1) * 200 + key] = v.y;
    Vt[(d0 + 2) * 200 + key] = v.z;
    Vt[(d0 + 3) * 200 + key] = v.w;
  }
  __syncthreads();

  const float sink = sinks[head];
  u16* slab = &Pslab[w * 32 * 40];
  f32x4 zz = {0.f, 0.f, 0.f, 0.f};

  for (int qs = 0; qs < 2; qs++) {
    const int qbase = s0 + qs * 32;   // query rows
    const int koff = qs * 32;         // staged-key window offset

    // ---- Q frags with in-register RoPE ----
    bf16x8 qf[2][2];
#pragma unroll
    for (int rt = 0; rt < 2; rt++) {
      int s = qbase + rt * 16 + lr;
      const u16* base = qkv + (size_t)s * QKV_N + head * 64 + lg * 8;
      u16x8 r0 = *(const u16x8*)(base);
      u16x8 r1 = *(const u16x8*)(base + 32);
      const float2* cs = tab + (size_t)s * 32 + lg * 8;
      u16x8 y0, y1;
#pragma unroll
      for (int jj = 0; jj < 8; jj++) {
        float f1 = bf2f(r0[jj]), f2 = bf2f(r1[jj]);
        float2 t = cs[jj];
        y0[jj] = f2bf(f1 * t.x - f2 * t.y);
        y1[jj] = f2bf(f2 * t.x + f1 * t.y);
      }
      qf[rt][0] = __builtin_bit_cast(bf16x8, y0);
      qf[rt][1] = __builtin_bit_cast(bf16x8, y1);
    }

    // ---- QK^T over this subtile's 160-key window ----
    f32x4 sc[2][10];
#pragma unroll
    for (int rt = 0; rt < 2; rt++)
#pragma unroll
      for (int nt = 0; nt < 10; nt++) sc[rt][nt] = zz;
#pragma unroll
    for (int nt = 0; nt < 10; nt++) {
      int key = koff + nt * 16 + lr;
#pragma unroll
      for (int ks = 0; ks < 2; ks++) {
        int off = (key * 128 + ks * 64 + lg * 16) ^ ((key & 7) << 4);
        bf16x8 kf = *(const bf16x8*)((const char*)Klds + off);
        sc[0][nt] = MFMA16(qf[0][ks], kf, sc[0][nt]);
        sc[1][nt] = MFMA16(qf[1][ks], kf, sc[1][nt]);
      }
    }

    // ---- mask + scale (subtile-local coords) ----
#pragma unroll
    for (int rt = 0; rt < 2; rt++)
#pragma unroll
      for (int nt = 0; nt < 10; nt++)
#pragma unroll
        for (int rg = 0; rg < 4; rg++) {
          int qq = rt * 16 + lg * 4 + rg;
          int jl = nt * 16 + lr;
          bool valid = (jl >= qq) && (jl <= qq + 127) && ((kb + koff + jl) >= 0);
          sc[rt][nt][rg] = valid ? sc[rt][nt][rg] * SCALE : NEGINF;
        }

    // ---- softmax ----
    float den[2][4];
#pragma unroll
    for (int rt = 0; rt < 2; rt++)
#pragma unroll
      for (int rg = 0; rg < 4; rg++) {
        float m = NEGINF;
#pragma unroll
        for (int nt = 0; nt < 10; nt++) m = fmaxf(m, sc[rt][nt][rg]);
#pragma unroll
        for (int x = 1; x < 16; x <<= 1) m = fmaxf(m, __shfl_xor(m, x, 64));
        m = fmaxf(m, sink);
        float sum = 0.f;
#pragma unroll
        for (int nt = 0; nt < 10; nt++) {
          float p = __expf(sc[rt][nt][rg] - m);
          sc[rt][nt][rg] = p;
          sum += p;
        }
#pragma unroll
        for (int x = 1; x < 16; x <<= 1) sum += __shfl_xor(sum, x, 64);
        den[rt][rg] = sum + __expf(sink - m);
      }

    // ---- PV over the window ----
    f32x4 oacc[2][4];
#pragma unroll
    for (int rt = 0; rt < 2; rt++)
#pragma unroll
      for (int dn = 0; dn < 4; dn++) oacc[rt][dn] = zz;
#pragma unroll
    for (int kt = 0; kt < 5; kt++) {
#pragma unroll
      for (int rt = 0; rt < 2; rt++)
#pragma unroll
        for (int j2 = 0; j2 < 2; j2++)
#pragma unroll
          for (int rg = 0; rg < 4; rg++)
            slab[(rt * 16 + lg * 4 + rg) * 40 + j2 * 16 + lr] =
                f2bf(sc[rt][kt * 2 + j2][rg]);
      asm volatile("s_waitcnt lgkmcnt(0)" ::: "memory");
      __builtin_amdgcn_sched_barrier(0);
      bf16x8 pf0 = *(const bf16x8*)&slab[lr * 40 + lg * 8];
      bf16x8 pf1 = *(const bf16x8*)&slab[(16 + lr) * 40 + lg * 8];
#pragma unroll
      for (int dn = 0; dn < 4; dn++) {
        bf16x8 vf = *(const bf16x8*)&Vt[(dn * 16 + lr) * 200 + koff + kt * 32 + lg * 8];
        oacc[0][dn] = MFMA16(pf0, vf, oacc[0][dn]);
        oacc[1][dn] = MFMA16(pf1, vf, oacc[1][dn]);
      }
    }

    // ---- write normalized output (bf16 for GEMM2) ----
#pragma unroll
    for (int rt = 0; rt < 2; rt++)
#pragma unroll
      for (int dn = 0; dn < 4; dn++)
#pragma unroll
        for (int rg = 0; rg < 4; rg++) {
          int s = qbase + rt * 16 + lg * 4 + rg;
          float val = oacc[rt][dn][rg] / den[rt][rg];
          out[(size_t)s * ATTN_K + head * 64 + dn * 16 + lr] = f2bf(val);
        }
  }
}

extern "C" void kernel_launch(void* const* d_in, const int* in_sizes, int n_in,
                              void* d_out, int out_size, void* d_ws, size_t ws_size,
                              hipStream_t stream) {
  const float* hs = (const float*)d_in[0];
  const int* pos = (const int*)d_in[1];
  const float* wqkv = (const float*)d_in[2];
  const float* bqkv = (const float*)d_in[3];
  const float* wo = (const float*)d_in[4];
  const float* bo = (const float*)d_in[5];
  const float* sinks = (const float*)d_in[6];
  float* out = (float*)d_out;

  char* ws = (char*)d_ws;
  u16* qkvb = (u16*)(ws + 0);               // 2048*5120*2 = 20,971,520 (bf16, un-roped)
  u16* hsb = (u16*)(ws + 41943040);         // 2048*2880*2 = 11,796,480 -> ends 53,739,520
  u16* wqkvT = (u16*)(ws + 53739520);       // 5120*2880*2 = 29,491,200 -> ends 83,230,720
  u16* attnb = (u16*)(ws + 41943040);       // 2048*4096*2 (aliases dead hsb/wqkvT)
  u16* woT = (u16*)(ws + 83230720);         // 2944*4096*2 = 24,117,248 -> ends 107,347,968
  float2* tab = (float2*)(ws + 107347968);  // 2048*32*8   = 524,288

  k_prep<<<32192, 256, 0, stream>>>(pos, tab, hs, hsb, wqkv, wqkvT, wo, woT);
  k_gemm1<<<512, 256, 0, stream>>>(hsb, wqkvT, bqkv, qkvb);
  k_attn<<<dim3(32, 8), 512, 0, stream>>>(qkvb, sinks, tab, attnb);
  k_gemm2<<<480, 256, 0, stream>>>(attnb, woT, bo, out);
}